// Round 12
// baseline (84.531 us; speedup 1.0000x reference)
//
#include <hip/hip_runtime.h>

typedef _Float16 f16;
typedef f16 f16x8 __attribute__((ext_vector_type(8)));
typedef f16 f16x4 __attribute__((ext_vector_type(4)));
typedef float f32x4 __attribute__((ext_vector_type(4)));

constexpr float ATT_SCALE = 0.17677669529663687f; // 1/sqrt(32)
constexpr float LOG2E = 1.4426950408889634f;

// ---------------- DPP wave-64 reductions ----------------
template<int C> __device__ __forceinline__ float dppadd(float v) {
    return v + __int_as_float(__builtin_amdgcn_update_dpp(0, __float_as_int(v), C, 0xf, 0xf, true));
}
template<int C> __device__ __forceinline__ float dppmax(float v) {
    return fmaxf(v, __int_as_float(__builtin_amdgcn_update_dpp(__float_as_int(v), __float_as_int(v), C, 0xf, 0xf, false)));
}
__device__ __forceinline__ float wave_sum(float v) {
    v = dppadd<0x111>(v); v = dppadd<0x112>(v); v = dppadd<0x114>(v); v = dppadd<0x118>(v);
    v = dppadd<0x142>(v); v = dppadd<0x143>(v);
    return __int_as_float(__builtin_amdgcn_readlane(__float_as_int(v), 63));
}
__device__ __forceinline__ float wave_max(float v) {
    v = dppmax<0x111>(v); v = dppmax<0x112>(v); v = dppmax<0x114>(v); v = dppmax<0x118>(v);
    v = dppmax<0x142>(v); v = dppmax<0x143>(v);
    return __int_as_float(__builtin_amdgcn_readlane(__float_as_int(v), 63));
}

// ------- prep: pool (bid<512) | x transpose (<1024) | weight cast+g-fold (<1536) | sg/sb -------
__global__ __launch_bounds__(256) void prep_kernel(const float* __restrict__ y,
                                                   float* __restrict__ pooled,
                                                   const float* __restrict__ x,
                                                   f16* __restrict__ xT,
                                                   const float* __restrict__ Wq,
                                                   const float* __restrict__ Wkv,
                                                   const float* __restrict__ Wp,
                                                   const float* __restrict__ lng,
                                                   const float* __restrict__ lnb,
                                                   f16* __restrict__ wq16,
                                                   f16* __restrict__ wkv16,
                                                   f16* __restrict__ wp16,
                                                   float* __restrict__ sg,
                                                   float* __restrict__ sb)
{
    __shared__ float sh[1444];
    int bid = blockIdx.x, t = threadIdx.x;
    if (bid < 512) {
        float (*p)[38] = (float(*)[38])sh;
        const float* plane = y + (size_t)bid * 1024;
        for (int i = t; i < 38 * 38; i += 256) (&p[0][0])[i] = 0.f;
        __syncthreads();
        for (int i = t; i < 1024; i += 256) p[(i >> 5) + 3][(i & 31) + 3] = plane[i];
        __syncthreads();
        int b = bid >> 8, c = bid & 255;
        for (int i = t; i < 1024; i += 256) {
            int r = (i >> 5) + 3, cc = (i & 31) + 3;
            float s3 = 0.f;
            #pragma unroll
            for (int dr = -1; dr <= 1; ++dr)
                #pragma unroll
                for (int dc = -1; dc <= 1; ++dc) s3 += p[r + dr][cc + dc];
            float r5 = 0.f;
            #pragma unroll
            for (int dc = -2; dc <= 2; ++dc) r5 += p[r - 2][cc + dc] + p[r + 2][cc + dc];
            #pragma unroll
            for (int dr = -1; dr <= 1; ++dr) r5 += p[r + dr][cc - 2] + p[r + dr][cc + 2];
            float r7 = 0.f;
            #pragma unroll
            for (int dc = -3; dc <= 3; ++dc) r7 += p[r - 3][cc + dc] + p[r + 3][cc + dc];
            #pragma unroll
            for (int dr = -2; dr <= 2; ++dr) r7 += p[r + dr][cc - 3] + p[r + dr][cc + 3];
            float s5 = s3 + r5, s7 = s5 + r7;
            pooled[((size_t)b * 1024 + i) * 256 + c] =
                s3 * (1.f / 9.f) + s5 * (1.f / 25.f) + s7 * (1.f / 49.f);
        }
    } else if (bid < 1024) {
        float (*tile)[33] = (float(*)[33])sh;
        int id = bid - 512;
        int b = id >> 8, ct = (id >> 5) & 7, nt = id & 31;
        int rr = t >> 5, j = t & 31;
        #pragma unroll
        for (int r = rr; r < 32; r += 8)
            tile[r][j] = x[((size_t)b * 256 + ct * 32 + r) * 1024 + nt * 32 + j];
        __syncthreads();
        #pragma unroll
        for (int r = rr; r < 32; r += 8)
            xT[((size_t)b * 1024 + nt * 32 + r) * 256 + ct * 32 + j] = (f16)tile[j][r];
    } else if (bid < 1536) {
        int i = (bid - 1024) * 256 + t;
        if (i < 65536) { wq16[i] = (f16)Wq[i]; wp16[i] = (f16)Wp[i]; }
        wkv16[i] = (f16)(Wkv[i] * lng[i & 255]);          // fold LN gamma into Wkv
    } else {
        int o = (bid - 1536) * 256 + t;                    // 512 rows of Wkv
        const float4* wr = (const float4*)(Wkv + (size_t)o * 256);
        const float4* gr = (const float4*)lng;
        const float4* br = (const float4*)lnb;
        float sgs = 0.f, sbs = 0.f;
        #pragma unroll 8
        for (int c4 = 0; c4 < 64; ++c4) {
            float4 wv = wr[c4], gv = gr[c4], bv = br[c4];
            sgs += wv.x * gv.x + wv.y * gv.y + wv.z * gv.z + wv.w * gv.w;
            sbs += wv.x * bv.x + wv.y * bv.y + wv.z * bv.z + wv.w * bv.w;
        }
        sg[o] = sgs; sb[o] = sbs;
    }
}

// ---------------- merged Q and KV projections; KV has LN folded algebraically ---------
__device__ __forceinline__ void gemm_tile(const f16* __restrict__ A, const f16* __restrict__ Bm,
                                          int row0, int ncol0, int l15, int lhi, f32x4 acc[4])
{
    for (int k0 = 0; k0 < 256; k0 += 32) {
        f16x8 a = *(const f16x8*)(A + (size_t)(row0 + l15) * 256 + k0 + lhi * 8);
        #pragma unroll
        for (int j = 0; j < 4; ++j) {
            f16x8 bf = *(const f16x8*)(Bm + (size_t)(ncol0 + j * 16 + l15) * 256 + k0 + lhi * 8);
            acc[j] = __builtin_amdgcn_mfma_f32_16x16x32_f16(a, bf, acc[j], 0, 0, 0);
        }
    }
}

__global__ __launch_bounds__(256) void qkv_kernel(const f16* __restrict__ xT,
                                                  const float* __restrict__ pooled,
                                                  const f16* __restrict__ wq16,
                                                  const f16* __restrict__ wkv16,
                                                  const float* __restrict__ sg,
                                                  const float* __restrict__ sb,
                                                  f16* __restrict__ q16,
                                                  f16* __restrict__ k16,
                                                  f16* __restrict__ vT16)
{
    int w = threadIdx.x >> 6, lane = threadIdx.x & 63;
    int l15 = lane & 15, lhi = lane >> 4;
    if (blockIdx.x < 128) {
        int mt = blockIdx.x >> 2, nt = blockIdx.x & 3;
        int row0 = mt * 64 + w * 16;
        f32x4 acc[4] = {};
        gemm_tile(xT, wq16, row0, nt * 64, l15, lhi, acc);
        #pragma unroll
        for (int j = 0; j < 4; ++j) {
            int col = nt * 64 + j * 16 + l15;
            int h = col >> 5, d = col & 31;
            #pragma unroll
            for (int r = 0; r < 4; ++r) {
                int row = row0 + 4 * lhi + r;
                int b = row >> 10, n = row & 1023;
                q16[(((size_t)(b * 8 + h)) * 1024 + n) * 32 + d] = (f16)(acc[j][r] * ATT_SCALE);
            }
        }
    } else {
        __shared__ float st_part[64][4][2];
        __shared__ float stats[64][2];                    // mu, rstd
        int bid = blockIdx.x - 128;
        int mt = bid >> 3, nt = bid & 7;
        int row0g = mt * 64;
        {
            int row = threadIdx.x >> 2, part = threadIdx.x & 3;
            const float4* pr = (const float4*)(pooled + (size_t)(row0g + row) * 256 + part * 64);
            float su = 0.f, qq = 0.f;
            #pragma unroll
            for (int i = 0; i < 16; ++i) {
                float4 v = pr[i];
                su += v.x + v.y + v.z + v.w;
                qq += v.x * v.x + v.y * v.y + v.z * v.z + v.w * v.w;
            }
            st_part[row][part][0] = su; st_part[row][part][1] = qq;
        }
        __syncthreads();
        if (threadIdx.x < 64) {
            int row = threadIdx.x;
            float su = st_part[row][0][0] + st_part[row][1][0] + st_part[row][2][0] + st_part[row][3][0];
            float qq = st_part[row][0][1] + st_part[row][1][1] + st_part[row][2][1] + st_part[row][3][1];
            float mu = su * (1.f / 256.f);
            float rstd = rsqrtf(qq * (1.f / 256.f) - mu * mu + 1e-5f);
            stats[row][0] = mu; stats[row][1] = rstd;
        }
        __syncthreads();
        f32x4 acc[4] = {};
        const float* Ap = pooled + (size_t)(row0g + w * 16 + l15) * 256;
        for (int k0 = 0; k0 < 256; k0 += 32) {
            float4 u0 = *(const float4*)(Ap + k0 + lhi * 8);
            float4 u1 = *(const float4*)(Ap + k0 + lhi * 8 + 4);
            f16x8 a;
            a[0] = (f16)u0.x; a[1] = (f16)u0.y; a[2] = (f16)u0.z; a[3] = (f16)u0.w;
            a[4] = (f16)u1.x; a[5] = (f16)u1.y; a[6] = (f16)u1.z; a[7] = (f16)u1.w;
            #pragma unroll
            for (int j = 0; j < 4; ++j) {
                f16x8 bf = *(const f16x8*)(wkv16 + (size_t)(nt * 64 + j * 16 + l15) * 256 + k0 + lhi * 8);
                acc[j] = __builtin_amdgcn_mfma_f32_16x16x32_f16(a, bf, acc[j], 0, 0, 0);
            }
        }
        float mu_r[4], rs_r[4];
        #pragma unroll
        for (int r = 0; r < 4; ++r) {
            int lr = w * 16 + 4 * lhi + r;
            mu_r[r] = stats[lr][0]; rs_r[r] = stats[lr][1];
        }
        #pragma unroll
        for (int j = 0; j < 4; ++j) {
            int col = nt * 64 + j * 16 + l15;
            float sgv = sg[col], sbv = sb[col];
            #pragma unroll
            for (int r = 0; r < 4; ++r) {
                int row = row0g + w * 16 + 4 * lhi + r;
                int b = row >> 10, n = row & 1023;
                float v = rs_r[r] * acc[j][r] - rs_r[r] * mu_r[r] * sgv + sbv;
                if (col < 256) {
                    int h = col >> 5, d = col & 31;
                    k16[(((size_t)(b * 8 + h)) * 1024 + n) * 32 + d] = (f16)v;
                } else {
                    int c2 = col - 256, h = c2 >> 5, d = c2 & 31;
                    vT16[(((size_t)(b * 8 + h)) * 32 + d) * 1024 + n] = (f16)v;
                }
            }
        }
    }
}

// ------ count of packed f16 values >= mh via ballot (v_cmp_ge_f16 + SALU popcount) ----
__device__ __forceinline__ int cnth(f16x8 a, f16x8 b, f16 mh)
{
    int c = 0;
    #pragma unroll
    for (int i = 0; i < 8; ++i) c += (int)__popcll(__ballot(a[i] >= mh));
    #pragma unroll
    for (int i = 0; i < 8; ++i) c += (int)__popcll(__ballot(b[i] >= mh));
    return c;
}

// branchless bracket widen from probe counts (f16-domain counting)
#define WIDENH(HA, HB, aa, bb, K, mn4, mxv, lo, hi, cl, ch) { \
    int _ca = cnth(HA, HB, (f16)(aa)); int _cb = cnth(HA, HB, (f16)(bb)); \
    bool _lm = _ca < (K); bool _hm = _cb > (K); \
    lo = _lm ? (mn4) : (_hm ? (bb) : (aa)); \
    hi = _lm ? (aa)  : (_hm ? (mxv) : (bb)); \
    cl = _lm ? 1024.f : (_hm ? (float)_cb : (float)_ca); \
    ch = _lm ? (float)_ca : (_hm ? 1.f : (float)_cb); }

// midpoint: alternate regula-falsi (clamped) / bisection
#define MID(it, lo, hi, cl, ch, K, m) { \
    if ((it) & 1) { m = 0.5f * (lo + hi); } \
    else { float _den = fmaxf(cl - ch, 1.0f); \
        m = lo + (hi - lo) * (cl - (float)(K)) * __builtin_amdgcn_rcpf(_den); \
        float _mg = 0.12f * (hi - lo); \
        m = fminf(fmaxf(m, lo + _mg), hi - _mg); } }

#define UPD(cv, K, lo, hi, cl, ch, m) { bool _g = (cv) >= (K); \
    lo = _g ? (m) : lo; cl = _g ? (float)(cv) : cl; \
    hi = _g ? hi : (m); ch = _g ? ch : (float)(cv); }

// -- fused attention v12: f16 ballot counting, 64-VGPR budget, 4 blocks/CU target -----
__global__ __launch_bounds__(512, 8) void attn_kernel(const f16* __restrict__ q16,
                                                      const f16* __restrict__ k16,
                                                      const f16* __restrict__ vT16,
                                                      const float* __restrict__ a1p,
                                                      const float* __restrict__ a2p,
                                                      f16* __restrict__ oat)
{
    __shared__ f16 Sb[16 * 1024];        // 32 KB, pair(8-elem)-swizzled
    int bid = blockIdx.x;
    int bh = bid >> 6, rb = bid & 63;
    int row0 = rb * 16;
    int w = threadIdx.x >> 6, lane = threadIdx.x & 63;   // w in [0,8)
    int l15 = lane & 15, lhi = lane >> 4;
    const f16* Qb = q16 + (size_t)bh * 32768;
    const f16* Kb = k16 + (size_t)bh * 32768;
    const f16* Vb = vT16 + (size_t)bh * 32768;

    // ---- phase 1: S = Q K^T (swapped mfma(K,Q)); f16 pair-swizzled stores
    {
        f16x8 qf = *(const f16x8*)(Qb + (size_t)(row0 + l15) * 32 + lhi * 8);
        int q = l15, sw1 = q & 7;
        int phalf = (lhi & 1) * 4;
        #pragma unroll
        for (int j = 0; j < 8; ++j) {
            int c0 = w * 128 + j * 16;
            f16x8 kf = *(const f16x8*)(Kb + (size_t)(c0 + l15) * 32 + lhi * 8);
            f32x4 z = {0.f, 0.f, 0.f, 0.f};
            f32x4 d = __builtin_amdgcn_mfma_f32_16x16x32_f16(kf, qf, z, 0, 0, 0);
            int pl = (c0 >> 3) + (lhi >> 1);
            int pp = pl ^ sw1;
            f16x4 hv;
            hv[0] = (f16)d[0]; hv[1] = (f16)d[1]; hv[2] = (f16)d[2]; hv[3] = (f16)d[3];
            *(f16x4*)(Sb + q * 1024 + pp * 8 + phalf) = hv;
        }
    }
    __syncthreads();

    // ---- phase 2: rows r0=2w, r1=2w+1; all state = 4 packed f16x8 regs (16 VGPR)
    float c_a1 = a1p[0], c_a2 = a2p[0];
    int r0 = 2 * w, r1 = r0 + 1;
    int cs0 = r0 & 7, cs1 = r1 & 7;
    f16x8 ha0 = *(const f16x8*)(Sb + r0 * 1024 + ((lane ^ cs0) << 3));
    f16x8 hb0 = *(const f16x8*)(Sb + r0 * 1024 + (((64 + lane) ^ cs0) << 3));
    f16x8 ha1 = *(const f16x8*)(Sb + r1 * 1024 + ((lane ^ cs1) << 3));
    f16x8 hb1 = *(const f16x8*)(Sb + r1 * 1024 + (((64 + lane) ^ cs1) << 3));

    // row stats (one-time f32 pass)
    float su0 = 0.f, qq0 = 0.f, mxl0 = -1e30f;
    float su1 = 0.f, qq1 = 0.f, mxl1 = -1e30f;
    #pragma unroll
    for (int i = 0; i < 8; ++i) {
        float v0 = (float)ha0[i], u0 = (float)hb0[i];
        su0 += v0 + u0; qq0 = fmaf(v0, v0, fmaf(u0, u0, qq0));
        mxl0 = fmaxf(mxl0, fmaxf(v0, u0));
        float v1 = (float)ha1[i], u1 = (float)hb1[i];
        su1 += v1 + u1; qq1 = fmaf(v1, v1, fmaf(u1, u1, qq1));
        mxl1 = fmaxf(mxl1, fmaxf(v1, u1));
    }
    float mx0 = wave_max(mxl0), mx1 = wave_max(mxl1);
    float mu0 = wave_sum(su0) * (1.f / 1024.f), mu1 = wave_sum(su1) * (1.f / 1024.f);
    float sg0 = sqrtf(fmaxf(wave_sum(qq0) * (1.f / 1024.f) - mu0 * mu0, 1e-30f));
    float sg1 = sqrtf(fmaxf(wave_sum(qq1) * (1.f / 1024.f) - mu1 * mu1, 1e-30f));

    // Gaussian-init brackets (z=0 for k=512, z=0.4316 for k=341), then 8 branchless iters
    float lo1, hi1, cl1, ch1, lo2, hi2, cl2, ch2;
    float lo3, hi3, cl3, ch3, lo4, hi4, cl4, ch4;
    {
        float d0 = 0.25f * sg0, d1 = 0.25f * sg1;
        float g0 = mu0 + 0.4316f * sg0, g1 = mu1 + 0.4316f * sg1;
        float mn40 = mu0 - 4.f * sg0, mn41 = mu1 - 4.f * sg1;
        WIDENH(ha0, hb0, mu0 - d0, mu0 + d0, 512, mn40, mx0, lo1, hi1, cl1, ch1);
        WIDENH(ha0, hb0, g0 - d0,  g0 + d0,  341, mn40, mx0, lo2, hi2, cl2, ch2);
        WIDENH(ha1, hb1, mu1 - d1, mu1 + d1, 512, mn41, mx1, lo3, hi3, cl3, ch3);
        WIDENH(ha1, hb1, g1 - d1,  g1 + d1,  341, mn41, mx1, lo4, hi4, cl4, ch4);
    }
    #pragma unroll
    for (int it = 0; it < 8; ++it) {
        float m1, m2, m3, m4;
        MID(it, lo1, hi1, cl1, ch1, 512, m1);
        MID(it, lo2, hi2, cl2, ch2, 341, m2);
        MID(it, lo3, hi3, cl3, ch3, 512, m3);
        MID(it, lo4, hi4, cl4, ch4, 341, m4);
        int c1 = cnth(ha0, hb0, (f16)m1);
        int c2 = cnth(ha0, hb0, (f16)m2);
        int c3 = cnth(ha1, hb1, (f16)m3);
        int c4 = cnth(ha1, hb1, (f16)m4);
        UPD(c1, 512, lo1, hi1, cl1, ch1, m1);
        UPD(c2, 341, lo2, hi2, cl2, ch2, m2);
        UPD(c3, 512, lo3, hi3, cl3, ch3, m3);
        UPD(c4, 341, lo4, hi4, cl4, ch4, m4);
    }

    // epilogue row r0 (f16 compares consistent with counting)
    {
        f16 m1h = (f16)lo1, m2h = (f16)lo2;
        float mxe = mx0 * LOG2E;
        float l1 = 0.f, l2 = 0.f;
        #pragma unroll
        for (int i = 0; i < 8; ++i) {
            float ev = exp2f(fmaf((float)ha0[i], LOG2E, -mxe));
            l1 += (ha0[i] >= m1h) ? ev : 0.f;
            l2 += (ha0[i] >= m2h) ? ev : 0.f;
            float ev2 = exp2f(fmaf((float)hb0[i], LOG2E, -mxe));
            l1 += (hb0[i] >= m1h) ? ev2 : 0.f;
            l2 += (hb0[i] >= m2h) ? ev2 : 0.f;
        }
        l1 = wave_sum(l1); l2 = wave_sum(l2);
        float w1 = c_a1 / l1, w2 = c_a2 / l2;
        f16x8 oa, ob;
        #pragma unroll
        for (int i = 0; i < 8; ++i) {
            float ev = exp2f(fmaf((float)ha0[i], LOG2E, -mxe));
            float wt = ((ha0[i] >= m1h) ? w1 : 0.f) + ((ha0[i] >= m2h) ? w2 : 0.f);
            oa[i] = (f16)(ev * wt);
            float ev2 = exp2f(fmaf((float)hb0[i], LOG2E, -mxe));
            float wt2 = ((hb0[i] >= m1h) ? w1 : 0.f) + ((hb0[i] >= m2h) ? w2 : 0.f);
            ob[i] = (f16)(ev2 * wt2);
        }
        *(f16x8*)(Sb + r0 * 1024 + ((lane ^ cs0) << 3)) = oa;
        *(f16x8*)(Sb + r0 * 1024 + (((64 + lane) ^ cs0) << 3)) = ob;
    }
    // epilogue row r1
    {
        f16 m3h = (f16)lo3, m4h = (f16)lo4;
        float mxe = mx1 * LOG2E;
        float l3 = 0.f, l4 = 0.f;
        #pragma unroll
        for (int i = 0; i < 8; ++i) {
            float ev = exp2f(fmaf((float)ha1[i], LOG2E, -mxe));
            l3 += (ha1[i] >= m3h) ? ev : 0.f;
            l4 += (ha1[i] >= m4h) ? ev : 0.f;
            float ev2 = exp2f(fmaf((float)hb1[i], LOG2E, -mxe));
            l3 += (hb1[i] >= m3h) ? ev2 : 0.f;
            l4 += (hb1[i] >= m4h) ? ev2 : 0.f;
        }
        l3 = wave_sum(l3); l4 = wave_sum(l4);
        float w3 = c_a1 / l3, w4 = c_a2 / l4;
        f16x8 oc, od;
        #pragma unroll
        for (int i = 0; i < 8; ++i) {
            float ev = exp2f(fmaf((float)ha1[i], LOG2E, -mxe));
            float wt = ((ha1[i] >= m3h) ? w3 : 0.f) + ((ha1[i] >= m4h) ? w4 : 0.f);
            oc[i] = (f16)(ev * wt);
            float ev2 = exp2f(fmaf((float)hb1[i], LOG2E, -mxe));
            float wt2 = ((hb1[i] >= m3h) ? w3 : 0.f) + ((hb1[i] >= m4h) ? w4 : 0.f);
            od[i] = (f16)(ev2 * wt2);
        }
        *(f16x8*)(Sb + r1 * 1024 + ((lane ^ cs1) << 3)) = oc;
        *(f16x8*)(Sb + r1 * 1024 + (((64 + lane) ^ cs1) << 3)) = od;
    }
    __syncthreads();

    // ---- phase 3: out = W V; wave w covers m-range [w*128, w*128+128)
    f32x4 acc0 = {}, acc1 = {};
    #pragma unroll
    for (int ks = 0; ks < 4; ++ks) {
        int pl = w * 16 + ks * 4 + lhi;
        int pp = pl ^ (l15 & 7);
        f16x8 af = *(const f16x8*)(Sb + l15 * 1024 + (pp << 3));
        int m0 = w * 128 + ks * 32 + lhi * 8;
        f16x8 b0 = *(const f16x8*)(Vb + (size_t)l15 * 1024 + m0);
        f16x8 b1v = *(const f16x8*)(Vb + (size_t)(16 + l15) * 1024 + m0);
        acc0 = __builtin_amdgcn_mfma_f32_16x16x32_f16(af, b0, acc0, 0, 0, 0);
        acc1 = __builtin_amdgcn_mfma_f32_16x16x32_f16(af, b1v, acc1, 0, 0, 0);
    }
    __syncthreads();
    float* Pf = (float*)Sb;              // reuse LDS as 8x512 f32 partials (16 KB)
    #pragma unroll
    for (int r2 = 0; r2 < 4; ++r2) {
        int rw = 4 * lhi + r2;
        Pf[w * 512 + rw * 32 + l15]      = acc0[r2];
        Pf[w * 512 + rw * 32 + 16 + l15] = acc1[r2];
    }
    __syncthreads();
    if (threadIdx.x < 128) {
        int o4 = threadIdx.x << 2;
        float4 v = *(const float4*)&Pf[o4];
        #pragma unroll
        for (int ww = 1; ww < 8; ++ww) {
            float4 p = *(const float4*)&Pf[ww * 512 + o4];
            v.x += p.x; v.y += p.y; v.z += p.z; v.w += p.w;
        }
        int rr = o4 >> 5, d0 = o4 & 31;
        int b = bh >> 3, h = bh & 7;
        f16x4 o;
        o[0] = (f16)v.x; o[1] = (f16)v.y; o[2] = (f16)v.z; o[3] = (f16)v.w;
        *(f16x4*)(oat + ((size_t)b * 1024 + row0 + rr) * 256 + h * 32 + d0) = o;
    }
}

// ---------------- output projection + bias, LDS-transposed coalesced writes ---------
__global__ __launch_bounds__(256) void projgemm_kernel(const f16* __restrict__ A,
                                                       const f16* __restrict__ Bm,
                                                       const float* __restrict__ bias,
                                                       float* __restrict__ out)
{
    __shared__ float tile[64][65];
    int mt = blockIdx.x >> 2, nt = blockIdx.x & 3;
    int w = threadIdx.x >> 6, lane = threadIdx.x & 63;
    int l15 = lane & 15, lhi = lane >> 4;
    int row0 = mt * 64 + w * 16;
    f32x4 acc[4] = {};
    gemm_tile(A, Bm, row0, nt * 64, l15, lhi, acc);
    #pragma unroll
    for (int j = 0; j < 4; ++j) {
        int col_l = j * 16 + l15;
        float bv = bias[nt * 64 + col_l];
        #pragma unroll
        for (int r = 0; r < 4; ++r)
            tile[col_l][w * 16 + 4 * lhi + r] = acc[j][r] + bv;
    }
    __syncthreads();
    int b = (mt * 64) >> 10, n0 = (mt * 64) & 1023;
    int col_l = threadIdx.x >> 2, part = threadIdx.x & 3;
    size_t base = (size_t)b * 262144 + (size_t)(nt * 64 + col_l) * 1024 + n0 + part * 16;
    #pragma unroll
    for (int q = 0; q < 4; ++q) {
        float4 v;
        v.x = tile[col_l][part * 16 + q * 4 + 0];
        v.y = tile[col_l][part * 16 + q * 4 + 1];
        v.z = tile[col_l][part * 16 + q * 4 + 2];
        v.w = tile[col_l][part * 16 + q * 4 + 3];
        *(float4*)(out + base + q * 4) = v;
    }
}

extern "C" void kernel_launch(void* const* d_in, const int* in_sizes, int n_in,
                              void* d_out, int out_size, void* d_ws, size_t ws_size,
                              hipStream_t stream)
{
    const float* x     = (const float*)d_in[0];
    const float* y     = (const float*)d_in[1];
    const float* Wq    = (const float*)d_in[2];
    const float* Wkv   = (const float*)d_in[3];
    const float* Wproj = (const float*)d_in[4];
    const float* bproj = (const float*)d_in[5];
    const float* ln_g  = (const float*)d_in[6];
    const float* ln_b  = (const float*)d_in[7];
    const float* a1p   = (const float*)d_in[8];
    const float* a2p   = (const float*)d_in[9];
    float* out = (float*)d_out;

    char* wsb = (char*)d_ws;
    float* pooled = (float*)(wsb);                                   // 2 MB [b][n][c] f32
    f16* xT    = (f16*)(wsb + ((size_t)2 << 20));                    // 1 MB
    f16* wq16  = (f16*)(wsb + ((size_t)3 << 20));                    // 128 KB
    f16* wkv16 = (f16*)(wsb + ((size_t)3 << 20) + (128 << 10));      // 256 KB
    f16* wp16  = (f16*)(wsb + ((size_t)3 << 20) + (384 << 10));      // 128 KB
    f16* q16   = (f16*)(wsb + ((size_t)3 << 20) + (512 << 10));      // 1 MB
    f16* k16   = (f16*)(wsb + ((size_t)3 << 20) + (512 << 10) + ((size_t)1 << 20));
    f16* vT16  = (f16*)(wsb + ((size_t)3 << 20) + (512 << 10) + ((size_t)2 << 20));
    f16* oat   = (f16*)(wsb + ((size_t)3 << 20) + (512 << 10) + ((size_t)3 << 20));
    float* sgp = (float*)(wsb + ((size_t)3 << 20) + (512 << 10) + ((size_t)4 << 20));
    float* sbp = sgp + 512;

    prep_kernel<<<1538, 256, 0, stream>>>(y, pooled, x, xT, Wq, Wkv, Wproj,
                                          ln_g, ln_b, wq16, wkv16, wp16, sgp, sbp);
    qkv_kernel<<<384, 256, 0, stream>>>(xT, pooled, wq16, wkv16, sgp, sbp,
                                        q16, k16, vT16);
    attn_kernel<<<1024, 512, 0, stream>>>(q16, k16, vT16, a1p, a2p, oat);
    projgemm_kernel<<<128, 256, 0, stream>>>(oat, wp16, bproj, out);
}

// Round 14
// 71.474 us; speedup vs baseline: 1.1827x; 1.1827x over previous
//
#include <hip/hip_runtime.h>

typedef _Float16 f16;
typedef f16 f16x8 __attribute__((ext_vector_type(8)));
typedef f16 f16x4 __attribute__((ext_vector_type(4)));
typedef float f32x4 __attribute__((ext_vector_type(4)));

constexpr float ATT_SCALE = 0.17677669529663687f; // 1/sqrt(32)

// ---------------- DPP wave-64 reductions ----------------
template<int C> __device__ __forceinline__ float dppadd(float v) {
    return v + __int_as_float(__builtin_amdgcn_update_dpp(0, __float_as_int(v), C, 0xf, 0xf, true));
}
template<int C> __device__ __forceinline__ float dppmax(float v) {
    return fmaxf(v, __int_as_float(__builtin_amdgcn_update_dpp(__float_as_int(v), __float_as_int(v), C, 0xf, 0xf, false)));
}
__device__ __forceinline__ float wave_sum(float v) {
    v = dppadd<0x111>(v); v = dppadd<0x112>(v); v = dppadd<0x114>(v); v = dppadd<0x118>(v);
    v = dppadd<0x142>(v); v = dppadd<0x143>(v);
    return __int_as_float(__builtin_amdgcn_readlane(__float_as_int(v), 63));
}
__device__ __forceinline__ float wave_max(float v) {
    v = dppmax<0x111>(v); v = dppmax<0x112>(v); v = dppmax<0x114>(v); v = dppmax<0x118>(v);
    v = dppmax<0x142>(v); v = dppmax<0x143>(v);
    return __int_as_float(__builtin_amdgcn_readlane(__float_as_int(v), 63));
}

// ------- prep: pool (bid<512) | x transpose (<1024) | weight cast+g-fold (<1536) | sg/sb -------
__global__ __launch_bounds__(256) void prep_kernel(const float* __restrict__ y,
                                                   float* __restrict__ pooled,
                                                   const float* __restrict__ x,
                                                   f16* __restrict__ xT,
                                                   const float* __restrict__ Wq,
                                                   const float* __restrict__ Wkv,
                                                   const float* __restrict__ Wp,
                                                   const float* __restrict__ lng,
                                                   const float* __restrict__ lnb,
                                                   f16* __restrict__ wq16,
                                                   f16* __restrict__ wkv16,
                                                   f16* __restrict__ wp16,
                                                   float* __restrict__ sg,
                                                   float* __restrict__ sb)
{
    __shared__ float sh[1444];
    int bid = blockIdx.x, t = threadIdx.x;
    if (bid < 512) {
        float (*p)[38] = (float(*)[38])sh;
        const float* plane = y + (size_t)bid * 1024;
        for (int i = t; i < 38 * 38; i += 256) (&p[0][0])[i] = 0.f;
        __syncthreads();
        for (int i = t; i < 1024; i += 256) p[(i >> 5) + 3][(i & 31) + 3] = plane[i];
        __syncthreads();
        int b = bid >> 8, c = bid & 255;
        for (int i = t; i < 1024; i += 256) {
            int r = (i >> 5) + 3, cc = (i & 31) + 3;
            float s3 = 0.f;
            #pragma unroll
            for (int dr = -1; dr <= 1; ++dr)
                #pragma unroll
                for (int dc = -1; dc <= 1; ++dc) s3 += p[r + dr][cc + dc];
            float r5 = 0.f;
            #pragma unroll
            for (int dc = -2; dc <= 2; ++dc) r5 += p[r - 2][cc + dc] + p[r + 2][cc + dc];
            #pragma unroll
            for (int dr = -1; dr <= 1; ++dr) r5 += p[r + dr][cc - 2] + p[r + dr][cc + 2];
            float r7 = 0.f;
            #pragma unroll
            for (int dc = -3; dc <= 3; ++dc) r7 += p[r - 3][cc + dc] + p[r + 3][cc + dc];
            #pragma unroll
            for (int dr = -2; dr <= 2; ++dr) r7 += p[r + dr][cc - 3] + p[r + dr][cc + 3];
            float s5 = s3 + r5, s7 = s5 + r7;
            pooled[((size_t)b * 1024 + i) * 256 + c] =
                s3 * (1.f / 9.f) + s5 * (1.f / 25.f) + s7 * (1.f / 49.f);
        }
    } else if (bid < 1024) {
        float (*tile)[33] = (float(*)[33])sh;
        int id = bid - 512;
        int b = id >> 8, ct = (id >> 5) & 7, nt = id & 31;
        int rr = t >> 5, j = t & 31;
        #pragma unroll
        for (int r = rr; r < 32; r += 8)
            tile[r][j] = x[((size_t)b * 256 + ct * 32 + r) * 1024 + nt * 32 + j];
        __syncthreads();
        #pragma unroll
        for (int r = rr; r < 32; r += 8)
            xT[((size_t)b * 1024 + nt * 32 + r) * 256 + ct * 32 + j] = (f16)tile[j][r];
    } else if (bid < 1536) {
        int i = (bid - 1024) * 256 + t;
        if (i < 65536) { wq16[i] = (f16)Wq[i]; wp16[i] = (f16)Wp[i]; }
        wkv16[i] = (f16)(Wkv[i] * lng[i & 255]);          // fold LN gamma into Wkv
    } else {
        int o = (bid - 1536) * 256 + t;                    // 512 rows of Wkv
        const float4* wr = (const float4*)(Wkv + (size_t)o * 256);
        const float4* gr = (const float4*)lng;
        const float4* br = (const float4*)lnb;
        float sgs = 0.f, sbs = 0.f;
        #pragma unroll 8
        for (int c4 = 0; c4 < 64; ++c4) {
            float4 wv = wr[c4], gv = gr[c4], bv = br[c4];
            sgs += wv.x * gv.x + wv.y * gv.y + wv.z * gv.z + wv.w * gv.w;
            sbs += wv.x * bv.x + wv.y * bv.y + wv.z * bv.z + wv.w * bv.w;
        }
        sg[o] = sgs; sb[o] = sbs;
    }
}

// ---------------- merged Q and KV projections; KV has LN folded algebraically ---------
__device__ __forceinline__ void gemm_tile(const f16* __restrict__ A, const f16* __restrict__ Bm,
                                          int row0, int ncol0, int l15, int lhi, f32x4 acc[4])
{
    for (int k0 = 0; k0 < 256; k0 += 32) {
        f16x8 a = *(const f16x8*)(A + (size_t)(row0 + l15) * 256 + k0 + lhi * 8);
        #pragma unroll
        for (int j = 0; j < 4; ++j) {
            f16x8 bf = *(const f16x8*)(Bm + (size_t)(ncol0 + j * 16 + l15) * 256 + k0 + lhi * 8);
            acc[j] = __builtin_amdgcn_mfma_f32_16x16x32_f16(a, bf, acc[j], 0, 0, 0);
        }
    }
}

__global__ __launch_bounds__(256) void qkv_kernel(const f16* __restrict__ xT,
                                                  const float* __restrict__ pooled,
                                                  const f16* __restrict__ wq16,
                                                  const f16* __restrict__ wkv16,
                                                  const float* __restrict__ sg,
                                                  const float* __restrict__ sb,
                                                  f16* __restrict__ q16,
                                                  f16* __restrict__ k16,
                                                  f16* __restrict__ vT16)
{
    int w = threadIdx.x >> 6, lane = threadIdx.x & 63;
    int l15 = lane & 15, lhi = lane >> 4;
    if (blockIdx.x < 128) {
        int mt = blockIdx.x >> 2, nt = blockIdx.x & 3;
        int row0 = mt * 64 + w * 16;
        f32x4 acc[4] = {};
        gemm_tile(xT, wq16, row0, nt * 64, l15, lhi, acc);
        #pragma unroll
        for (int j = 0; j < 4; ++j) {
            int col = nt * 64 + j * 16 + l15;
            int h = col >> 5, d = col & 31;
            #pragma unroll
            for (int r = 0; r < 4; ++r) {
                int row = row0 + 4 * lhi + r;
                int b = row >> 10, n = row & 1023;
                q16[(((size_t)(b * 8 + h)) * 1024 + n) * 32 + d] = (f16)(acc[j][r] * ATT_SCALE);
            }
        }
    } else {
        __shared__ float st_part[64][4][2];
        __shared__ float stats[64][2];                    // mu, rstd
        int bid = blockIdx.x - 128;
        int mt = bid >> 3, nt = bid & 7;
        int row0g = mt * 64;
        {
            int row = threadIdx.x >> 2, part = threadIdx.x & 3;
            const float4* pr = (const float4*)(pooled + (size_t)(row0g + row) * 256 + part * 64);
            float su = 0.f, qq = 0.f;
            #pragma unroll
            for (int i = 0; i < 16; ++i) {
                float4 v = pr[i];
                su += v.x + v.y + v.z + v.w;
                qq += v.x * v.x + v.y * v.y + v.z * v.z + v.w * v.w;
            }
            st_part[row][part][0] = su; st_part[row][part][1] = qq;
        }
        __syncthreads();
        if (threadIdx.x < 64) {
            int row = threadIdx.x;
            float su = st_part[row][0][0] + st_part[row][1][0] + st_part[row][2][0] + st_part[row][3][0];
            float qq = st_part[row][0][1] + st_part[row][1][1] + st_part[row][2][1] + st_part[row][3][1];
            float mu = su * (1.f / 256.f);
            float rstd = rsqrtf(qq * (1.f / 256.f) - mu * mu + 1e-5f);
            stats[row][0] = mu; stats[row][1] = rstd;
        }
        __syncthreads();
        f32x4 acc[4] = {};
        const float* Ap = pooled + (size_t)(row0g + w * 16 + l15) * 256;
        for (int k0 = 0; k0 < 256; k0 += 32) {
            float4 u0 = *(const float4*)(Ap + k0 + lhi * 8);
            float4 u1 = *(const float4*)(Ap + k0 + lhi * 8 + 4);
            f16x8 a;
            a[0] = (f16)u0.x; a[1] = (f16)u0.y; a[2] = (f16)u0.z; a[3] = (f16)u0.w;
            a[4] = (f16)u1.x; a[5] = (f16)u1.y; a[6] = (f16)u1.z; a[7] = (f16)u1.w;
            #pragma unroll
            for (int j = 0; j < 4; ++j) {
                f16x8 bf = *(const f16x8*)(wkv16 + (size_t)(nt * 64 + j * 16 + l15) * 256 + k0 + lhi * 8);
                acc[j] = __builtin_amdgcn_mfma_f32_16x16x32_f16(a, bf, acc[j], 0, 0, 0);
            }
        }
        float mu_r[4], rs_r[4];
        #pragma unroll
        for (int r = 0; r < 4; ++r) {
            int lr = w * 16 + 4 * lhi + r;
            mu_r[r] = stats[lr][0]; rs_r[r] = stats[lr][1];
        }
        #pragma unroll
        for (int j = 0; j < 4; ++j) {
            int col = nt * 64 + j * 16 + l15;
            float sgv = sg[col], sbv = sb[col];
            #pragma unroll
            for (int r = 0; r < 4; ++r) {
                int row = row0g + w * 16 + 4 * lhi + r;
                int b = row >> 10, n = row & 1023;
                float v = rs_r[r] * acc[j][r] - rs_r[r] * mu_r[r] * sgv + sbv;
                if (col < 256) {
                    int h = col >> 5, d = col & 31;
                    k16[(((size_t)(b * 8 + h)) * 1024 + n) * 32 + d] = (f16)v;
                } else {
                    int c2 = col - 256, h = c2 >> 5, d = c2 & 31;
                    vT16[(((size_t)(b * 8 + h)) * 32 + d) * 1024 + n] = (f16)v;
                }
            }
        }
    }
}

// ---------------- count of s[i] >= m across the wave (ballot/popc) ----------------
__device__ __forceinline__ int cnt16(const float* s, float m)
{
    int c = 0;
    #pragma unroll
    for (int i = 0; i < 16; ++i)
        c += (int)__popcll(__ballot(s[i] >= m));
    return c;
}

// branchless bracket widen from probe counts
#define WIDEN(sarr, aa, bb, K, mn4, mxv, lo, hi, cl, ch) { \
    int _ca = cnt16(sarr, (aa)); int _cb = cnt16(sarr, (bb)); \
    bool _lm = _ca < (K); bool _hm = _cb > (K); \
    lo = _lm ? (mn4) : (_hm ? (bb) : (aa)); \
    hi = _lm ? (aa)  : (_hm ? (mxv) : (bb)); \
    cl = _lm ? 1024.f : (_hm ? (float)_cb : (float)_ca); \
    ch = _lm ? (float)_ca : (_hm ? 1.f : (float)_cb); }

// midpoint: alternate regula-falsi (clamped) / bisection — bisection steps guarantee
// geometric bracket shrink even when RF stalls (r13 failure mode)
#define MID(it, lo, hi, cl, ch, K, m) { \
    if ((it) & 1) { m = 0.5f * (lo + hi); } \
    else { float _den = fmaxf(cl - ch, 1.0f); \
        m = lo + (hi - lo) * (cl - (float)(K)) * __builtin_amdgcn_rcpf(_den); \
        float _mg = 0.12f * (hi - lo); \
        m = fminf(fmaxf(m, lo + _mg), hi - _mg); } }

#define UPD(cv, K, lo, hi, cl, ch, m) { bool _g = (cv) >= (K); \
    lo = _g ? (m) : lo; cl = _g ? (float)(cv) : cl; \
    hi = _g ? hi : (m); ch = _g ? ch : (float)(cv); }

// ---- fused attention v14: r11 structure, 6 alternating iterations (32 counts/wave) ---
__global__ __launch_bounds__(512, 4) void attn_kernel(const f16* __restrict__ q16,
                                                      const f16* __restrict__ k16,
                                                      const f16* __restrict__ vT16,
                                                      const float* __restrict__ a1p,
                                                      const float* __restrict__ a2p,
                                                      f16* __restrict__ oat)
{
    __shared__ f16 Sb[16 * 1024];        // 32 KB, pair(8-elem)-swizzled
    int bid = blockIdx.x;
    int bh = bid >> 6, rb = bid & 63;
    int row0 = rb * 16;
    int w = threadIdx.x >> 6, lane = threadIdx.x & 63;   // w in [0,8)
    int l15 = lane & 15, lhi = lane >> 4;
    const f16* Qb = q16 + (size_t)bh * 32768;
    const f16* Kb = k16 + (size_t)bh * 32768;
    const f16* Vb = vT16 + (size_t)bh * 32768;

    // ---- phase 1: S = Q K^T (swapped mfma(K,Q)); f16 pair-swizzled stores
    {
        f16x8 qf = *(const f16x8*)(Qb + (size_t)(row0 + l15) * 32 + lhi * 8);
        int q = l15, sw1 = q & 7;
        int phalf = (lhi & 1) * 4;
        #pragma unroll
        for (int j = 0; j < 8; ++j) {
            int c0 = w * 128 + j * 16;
            f16x8 kf = *(const f16x8*)(Kb + (size_t)(c0 + l15) * 32 + lhi * 8);
            f32x4 z = {0.f, 0.f, 0.f, 0.f};
            f32x4 d = __builtin_amdgcn_mfma_f32_16x16x32_f16(kf, qf, z, 0, 0, 0);
            int pl = (c0 >> 3) + (lhi >> 1);
            int pp = pl ^ sw1;
            f16x4 hv;
            hv[0] = (f16)d[0]; hv[1] = (f16)d[1]; hv[2] = (f16)d[2]; hv[3] = (f16)d[3];
            *(f16x4*)(Sb + q * 1024 + pp * 8 + phalf) = hv;
        }
    }
    __syncthreads();

    // ---- phase 2: rows r0=2w, r1=2w+1; 4 searches interleaved, all state in regs
    float c_a1 = a1p[0], c_a2 = a2p[0];
    int r0 = 2 * w, r1 = r0 + 1;
    int cs0 = r0 & 7, cs1 = r1 & 7;
    float s0[16], s1[16];
    {
        f16x8 ha = *(const f16x8*)(Sb + r0 * 1024 + ((lane ^ cs0) << 3));
        f16x8 hb = *(const f16x8*)(Sb + r0 * 1024 + (((64 + lane) ^ cs0) << 3));
        f16x8 hc = *(const f16x8*)(Sb + r1 * 1024 + ((lane ^ cs1) << 3));
        f16x8 hd = *(const f16x8*)(Sb + r1 * 1024 + (((64 + lane) ^ cs1) << 3));
        #pragma unroll
        for (int i = 0; i < 8; ++i) {
            s0[i] = (float)ha[i]; s0[8 + i] = (float)hb[i];
            s1[i] = (float)hc[i]; s1[8 + i] = (float)hd[i];
        }
    }
    // stats
    float mx0l = s0[0], mx1l = s1[0];
    float su0 = 0.f, q0 = 0.f, su1 = 0.f, q1 = 0.f;
    #pragma unroll
    for (int i = 0; i < 16; ++i) {
        mx0l = fmaxf(mx0l, s0[i]); su0 += s0[i]; q0 = fmaf(s0[i], s0[i], q0);
        mx1l = fmaxf(mx1l, s1[i]); su1 += s1[i]; q1 = fmaf(s1[i], s1[i], q1);
    }
    float mx0 = wave_max(mx0l), mx1 = wave_max(mx1l);
    float mu0 = wave_sum(su0) * (1.f / 1024.f), mu1 = wave_sum(su1) * (1.f / 1024.f);
    float sg0 = sqrtf(fmaxf(wave_sum(q0) * (1.f / 1024.f) - mu0 * mu0, 1e-30f));
    float sg1 = sqrtf(fmaxf(wave_sum(q1) * (1.f / 1024.f) - mu1 * mu1, 1e-30f));

    // Gaussian-init brackets: z=0 for k=512, z=0.4316 for k=341
    float lo1, hi1, cl1, ch1, lo2, hi2, cl2, ch2;
    float lo3, hi3, cl3, ch3, lo4, hi4, cl4, ch4;
    {
        float d0 = 0.25f * sg0, d1 = 0.25f * sg1;
        float g0 = mu0 + 0.4316f * sg0, g1 = mu1 + 0.4316f * sg1;
        float mn40 = mu0 - 4.f * sg0, mn41 = mu1 - 4.f * sg1;
        WIDEN(s0, mu0 - d0, mu0 + d0, 512, mn40, mx0, lo1, hi1, cl1, ch1);
        WIDEN(s0, g0 - d0,  g0 + d0,  341, mn40, mx0, lo2, hi2, cl2, ch2);
        WIDEN(s1, mu1 - d1, mu1 + d1, 512, mn41, mx1, lo3, hi3, cl3, ch3);
        WIDEN(s1, g1 - d1,  g1 + d1,  341, mn41, mx1, lo4, hi4, cl4, ch4);
    }
    #pragma unroll
    for (int it = 0; it < 6; ++it) {
        float m1, m2, m3, m4;
        MID(it, lo1, hi1, cl1, ch1, 512, m1);
        MID(it, lo2, hi2, cl2, ch2, 341, m2);
        MID(it, lo3, hi3, cl3, ch3, 512, m3);
        MID(it, lo4, hi4, cl4, ch4, 341, m4);
        int c1 = cnt16(s0, m1);
        int c2 = cnt16(s0, m2);
        int c3 = cnt16(s1, m3);
        int c4 = cnt16(s1, m4);
        UPD(c1, 512, lo1, hi1, cl1, ch1, m1);
        UPD(c2, 341, lo2, hi2, cl2, ch2, m2);
        UPD(c3, 512, lo3, hi3, cl3, ch3, m3);
        UPD(c4, 341, lo4, hi4, cl4, ch4, m4);
    }
    // T = lo (count(>=lo) >= k, within small residual of k)
    {
        float t1a[16], t2a[16];
        float l1 = 0.f, l2 = 0.f;
        #pragma unroll
        for (int i = 0; i < 16; ++i) {
            float ev = __expf(s0[i] - mx0);
            float u1 = (s0[i] >= lo1) ? ev : 0.f;
            float u2 = (s0[i] >= lo2) ? ev : 0.f;
            t1a[i] = u1; t2a[i] = u2;
            l1 += u1; l2 += u2;
        }
        l1 = wave_sum(l1); l2 = wave_sum(l2);
        float w1 = c_a1 / l1, w2 = c_a2 / l2;
        f16x8 oa, ob;
        #pragma unroll
        for (int i = 0; i < 8; ++i) {
            oa[i] = (f16)(t1a[i] * w1 + t2a[i] * w2);
            ob[i] = (f16)(t1a[8 + i] * w1 + t2a[8 + i] * w2);
        }
        *(f16x8*)(Sb + r0 * 1024 + ((lane ^ cs0) << 3)) = oa;
        *(f16x8*)(Sb + r0 * 1024 + (((64 + lane) ^ cs0) << 3)) = ob;
    }
    {
        float t1b[16], t2b[16];
        float l3 = 0.f, l4 = 0.f;
        #pragma unroll
        for (int i = 0; i < 16; ++i) {
            float ev = __expf(s1[i] - mx1);
            float u1 = (s1[i] >= lo3) ? ev : 0.f;
            float u2 = (s1[i] >= lo4) ? ev : 0.f;
            t1b[i] = u1; t2b[i] = u2;
            l3 += u1; l4 += u2;
        }
        l3 = wave_sum(l3); l4 = wave_sum(l4);
        float w3 = c_a1 / l3, w4 = c_a2 / l4;
        f16x8 oc, od;
        #pragma unroll
        for (int i = 0; i < 8; ++i) {
            oc[i] = (f16)(t1b[i] * w3 + t2b[i] * w4);
            od[i] = (f16)(t1b[8 + i] * w3 + t2b[8 + i] * w4);
        }
        *(f16x8*)(Sb + r1 * 1024 + ((lane ^ cs1) << 3)) = oc;
        *(f16x8*)(Sb + r1 * 1024 + (((64 + lane) ^ cs1) << 3)) = od;
    }
    __syncthreads();

    // ---- phase 3: out = W V; wave w covers m-range [w*128, w*128+128)
    f32x4 acc0 = {}, acc1 = {};
    #pragma unroll
    for (int ks = 0; ks < 4; ++ks) {
        int pl = w * 16 + ks * 4 + lhi;
        int pp = pl ^ (l15 & 7);
        f16x8 af = *(const f16x8*)(Sb + l15 * 1024 + (pp << 3));
        int m0 = w * 128 + ks * 32 + lhi * 8;
        f16x8 b0 = *(const f16x8*)(Vb + (size_t)l15 * 1024 + m0);
        f16x8 b1v = *(const f16x8*)(Vb + (size_t)(16 + l15) * 1024 + m0);
        acc0 = __builtin_amdgcn_mfma_f32_16x16x32_f16(af, b0, acc0, 0, 0, 0);
        acc1 = __builtin_amdgcn_mfma_f32_16x16x32_f16(af, b1v, acc1, 0, 0, 0);
    }
    __syncthreads();
    float* Pf = (float*)Sb;              // reuse LDS as 8x512 f32 partials (16 KB)
    #pragma unroll
    for (int r2 = 0; r2 < 4; ++r2) {
        int rw = 4 * lhi + r2;
        Pf[w * 512 + rw * 32 + l15]      = acc0[r2];
        Pf[w * 512 + rw * 32 + 16 + l15] = acc1[r2];
    }
    __syncthreads();
    if (threadIdx.x < 128) {
        int o4 = threadIdx.x << 2;
        float4 v = *(const float4*)&Pf[o4];
        #pragma unroll
        for (int ww = 1; ww < 8; ++ww) {
            float4 p = *(const float4*)&Pf[ww * 512 + o4];
            v.x += p.x; v.y += p.y; v.z += p.z; v.w += p.w;
        }
        int rr = o4 >> 5, d0 = o4 & 31;
        int b = bh >> 3, h = bh & 7;
        f16x4 o;
        o[0] = (f16)v.x; o[1] = (f16)v.y; o[2] = (f16)v.z; o[3] = (f16)v.w;
        *(f16x4*)(oat + ((size_t)b * 1024 + row0 + rr) * 256 + h * 32 + d0) = o;
    }
}

// ---------------- output projection + bias, LDS-transposed coalesced writes ---------
__global__ __launch_bounds__(256) void projgemm_kernel(const f16* __restrict__ A,
                                                       const f16* __restrict__ Bm,
                                                       const float* __restrict__ bias,
                                                       float* __restrict__ out)
{
    __shared__ float tile[64][65];
    int mt = blockIdx.x >> 2, nt = blockIdx.x & 3;
    int w = threadIdx.x >> 6, lane = threadIdx.x & 63;
    int l15 = lane & 15, lhi = lane >> 4;
    int row0 = mt * 64 + w * 16;
    f32x4 acc[4] = {};
    gemm_tile(A, Bm, row0, nt * 64, l15, lhi, acc);
    #pragma unroll
    for (int j = 0; j < 4; ++j) {
        int col_l = j * 16 + l15;
        float bv = bias[nt * 64 + col_l];
        #pragma unroll
        for (int r = 0; r < 4; ++r)
            tile[col_l][w * 16 + 4 * lhi + r] = acc[j][r] + bv;
    }
    __syncthreads();
    int b = (mt * 64) >> 10, n0 = (mt * 64) & 1023;
    int col_l = threadIdx.x >> 2, part = threadIdx.x & 3;
    size_t base = (size_t)b * 262144 + (size_t)(nt * 64 + col_l) * 1024 + n0 + part * 16;
    #pragma unroll
    for (int q = 0; q < 4; ++q) {
        float4 v;
        v.x = tile[col_l][part * 16 + q * 4 + 0];
        v.y = tile[col_l][part * 16 + q * 4 + 1];
        v.z = tile[col_l][part * 16 + q * 4 + 2];
        v.w = tile[col_l][part * 16 + q * 4 + 3];
        *(float4*)(out + base + q * 4) = v;
    }
}

extern "C" void kernel_launch(void* const* d_in, const int* in_sizes, int n_in,
                              void* d_out, int out_size, void* d_ws, size_t ws_size,
                              hipStream_t stream)
{
    const float* x     = (const float*)d_in[0];
    const float* y     = (const float*)d_in[1];
    const float* Wq    = (const float*)d_in[2];
    const float* Wkv   = (const float*)d_in[3];
    const float* Wproj = (const float*)d_in[4];
    const float* bproj = (const float*)d_in[5];
    const float* ln_g  = (const float*)d_in[6];
    const float* ln_b  = (const float*)d_in[7];
    const float* a1p   = (const float*)d_in[8];
    const float* a2p   = (const float*)d_in[9];
    float* out = (float*)d_out;

    char* wsb = (char*)d_ws;
    float* pooled = (float*)(wsb);                                   // 2 MB [b][n][c] f32
    f16* xT    = (f16*)(wsb + ((size_t)2 << 20));                    // 1 MB
    f16* wq16  = (f16*)(wsb + ((size_t)3 << 20));                    // 128 KB
    f16* wkv16 = (f16*)(wsb + ((size_t)3 << 20) + (128 << 10));      // 256 KB
    f16* wp16  = (f16*)(wsb + ((size_t)3 << 20) + (384 << 10));      // 128 KB
    f16* q16   = (f16*)(wsb + ((size_t)3 << 20) + (512 << 10));      // 1 MB
    f16* k16   = (f16*)(wsb + ((size_t)3 << 20) + (512 << 10) + ((size_t)1 << 20));
    f16* vT16  = (f16*)(wsb + ((size_t)3 << 20) + (512 << 10) + ((size_t)2 << 20));
    f16* oat   = (f16*)(wsb + ((size_t)3 << 20) + (512 << 10) + ((size_t)3 << 20));
    float* sgp = (float*)(wsb + ((size_t)3 << 20) + (512 << 10) + ((size_t)4 << 20));
    float* sbp = sgp + 512;

    prep_kernel<<<1538, 256, 0, stream>>>(y, pooled, x, xT, Wq, Wkv, Wproj,
                                          ln_g, ln_b, wq16, wkv16, wp16, sgp, sbp);
    qkv_kernel<<<384, 256, 0, stream>>>(xT, pooled, wq16, wkv16, sgp, sbp,
                                        q16, k16, vT16);
    attn_kernel<<<1024, 512, 0, stream>>>(q16, k16, vT16, a1p, a2p, oat);
    projgemm_kernel<<<128, 256, 0, stream>>>(oat, wp16, bproj, out);
}